// Round 7
// baseline (1028.327 us; speedup 1.0000x reference)
//
#include <hip/hip_runtime.h>
#include <hip/hip_bf16.h>

// R20: k_attn zero-move P (eliminate plds round-trip).
// R19 post-mortem: halving staged VMEM bought ~0 -> LDS pipe + serial chain
// bound.  plds was 64KB/iter of 208KB/iter LDS traffic plus two scheduler
// fences.  Fix: exploit MFMA's k-slot freedom -- any bijection kv<->(quad,e)
// works if A and B agree.  Choose kv(quad,e)=32h+16(e>>2)+4quad+(e&3):
// B-operand (P) = this lane's own exp2(sA) packed in-register (no cross-lane
// move); A-operand (V) read as 2x ds_read_b64 per (h,dd) at cols
// (64h+8quad)^swz, (+32)^swz (each inside one 16B granule -> swizzle valid;
// bank spread = perfect 4x4B/bank).  Deletes 8 ds_write+4 ds_read/wave/iter
// and both asm-memory fences; frees 32KB LDS.  Rest identical to R19.
// B=8, C=512, N=1024, NH=8, HD=64.

#define B_  8
#define C_  512
#define N_  1024
#define NH_ 8
#define HD_ 64

typedef __bf16 bf16x8 __attribute__((ext_vector_type(8)));
typedef __bf16 bf16x4 __attribute__((ext_vector_type(4)));
typedef float  f32x4  __attribute__((ext_vector_type(4)));

#define MFMA16(a, b, c) __builtin_amdgcn_mfma_f32_16x16x32_bf16((a), (b), (c), 0, 0, 0)

__device__ __forceinline__ void gload16(const void* g, void* l) {
    __builtin_amdgcn_global_load_lds(
        (const __attribute__((address_space(1))) unsigned int*)g,
        (__attribute__((address_space(3))) unsigned int*)l, 16, 0, 0);
}

// -------------------- K0: merged prep.  blk<1024: x -> xt; else weights -> wcat
__global__ __launch_bounds__(256) void k_prep(const float* __restrict__ x,
                                              const float* __restrict__ wq,
                                              const float* __restrict__ wk,
                                              const float* __restrict__ wv,
                                              const float* __restrict__ wo,
                                              __bf16* __restrict__ xt,
                                              __bf16* __restrict__ wcat) {
    __shared__ float tile[64][68];
    int blk = blockIdx.x;
    int tid = threadIdx.x;
    if (blk < 1024) {
        int b   = blk >> 7;
        int rem = blk & 127;
        int ct  = rem >> 4;
        int pt  = rem & 15;
        int c0 = ct * 64, p0 = pt * 64;
        for (int i = 0; i < 4; ++i) {
            int vi = i * 256 + tid;
            int c = vi >> 4, p4 = (vi & 15) * 4;
            f32x4 v = *(const f32x4*)(x + ((size_t)(b * C_ + c0 + c)) * N_ + p0 + p4);
            *(f32x4*)&tile[c][p4] = v;
        }
        __syncthreads();
        for (int i = 0; i < 4; ++i) {
            int vi = i * 256 + tid;
            int p = vi >> 4, c4 = (vi & 15) * 4;
            bf16x4 v;
            for (int j = 0; j < 4; ++j) v[j] = (__bf16)tile[c4 + j][p];
            *(bf16x4*)(xt + ((size_t)(b * N_ + p0 + p)) * C_ + c0 + c4) = v;
        }
    } else {
        int idx = (blk - 1024) * 256 + tid;
        int mat = idx >> 16;
        int off = (idx & 65535) * 4;
        const float* w = (mat == 0) ? wq : (mat == 1) ? wk : (mat == 2) ? wv : wo;
        f32x4 v = *(const f32x4*)(w + off);
        bf16x4 o;
        for (int j = 0; j < 4; ++j) o[j] = (__bf16)v[j];
        *(bf16x4*)(wcat + (size_t)mat * 262144 + off) = o;
    }
}

// ------------------------------------------------- K1: QKV projection (MFMA)
// 128x128 tile, BK=32, triple-buffered gload_lds staging, counted vmcnt.
__global__ __launch_bounds__(256) void k_qkv(const __bf16* __restrict__ xt,
                                             const __bf16* __restrict__ wcat,
                                             __bf16* __restrict__ qa,
                                             __bf16* __restrict__ ka,
                                             __bf16* __restrict__ vt) {
    __shared__ __bf16 As[3][4096];               // 3 x 8KB (128 rows x 64B)
    __shared__ __bf16 Bs[3][4096];
    int blk  = blockIdx.x;
    int mat  = blk >> 8;
    int rem  = blk & 255;
    int b    = rem >> 5;
    int tile = rem & 31;
    int tid = threadIdx.x, lane = tid & 63, wid = tid >> 6;
    int quad = lane >> 4, l16 = lane & 15;

    const __bf16* w = wcat + (size_t)mat * 262144;
    const __bf16 *A, *Bm;
    int am0, bn0;
    if (mat < 2) {
        int mt = tile >> 2, nt = tile & 3;
        A   = xt + (size_t)b * N_ * C_;  am0 = mt * 128;
        Bm  = w;                         bn0 = nt * 128;
    } else {
        int mt = tile & 3, nt = tile >> 2;
        A   = w;                         am0 = mt * 128;
        Bm  = xt + (size_t)b * N_ * C_;  bn0 = nt * 128;
    }
    int wr = (wid >> 1) * 64, wc = (wid & 1) * 64;   // wave tile offsets

    int lrow = wid * 16 + (lane >> 2);
    int scol = ((lane & 3) * 16) ^ ((lrow & 3) << 4);
    const char* aS0 = (const char*)A  + (size_t)(am0 + lrow) * 1024 + scol;
    const char* aS1 = aS0 + 65536;                   // +64 rows
    const char* bS0 = (const char*)Bm + (size_t)(bn0 + lrow) * 1024 + scol;
    const char* bS1 = bS0 + 65536;
    int wb = wid * 1024;

    // rotating buffer base pointers: R=read, N=next (landed), P=prefetch-dest
    char *aR = (char*)&As[0][0], *aN = (char*)&As[1][0], *aP = (char*)&As[2][0];
    char *bR = (char*)&Bs[0][0], *bN = (char*)&Bs[1][0], *bP = (char*)&Bs[2][0];

    // prologue: tiles 0,1 -> R,N (8 loads); wait tile0 (vmcnt<=4); barrier
    gload16(aS0,      aR + wb);  gload16(aS1,      aR + wb + 4096);
    gload16(bS0,      bR + wb);  gload16(bS1,      bR + wb + 4096);
    gload16(aS0 + 64, aN + wb);  gload16(aS1 + 64, aN + wb + 4096);
    gload16(bS0 + 64, bN + wb);  gload16(bS1 + 64, bN + wb + 4096);
    asm volatile("s_waitcnt vmcnt(4)" ::: "memory");
    __builtin_amdgcn_s_barrier();

    f32x4 acc[4][4] = {};
    const int fo = (quad * 16) ^ ((l16 & 3) << 4);   // frag byte col (swz'd)
    for (int t = 0; t < 16; ++t) {
        int kb = ((t + 2) & 15) * 64;                // tile t+2 byte offset
        gload16(aS0 + kb, aP + wb);  gload16(aS1 + kb, aP + wb + 4096);
        gload16(bS0 + kb, bP + wb);  gload16(bS1 + kb, bP + wb + 4096);

        bf16x8 af[4], bfr[4];
        for (int i = 0; i < 4; ++i)
            af[i]  = *(const bf16x8*)(aR + (wr + i * 16 + l16) * 64 + fo);
        for (int i = 0; i < 4; ++i)
            bfr[i] = *(const bf16x8*)(bR + (wc + i * 16 + l16) * 64 + fo);
        for (int mi = 0; mi < 4; ++mi)
            for (int ni = 0; ni < 4; ++ni)
                acc[mi][ni] = MFMA16(af[mi], bfr[ni], acc[mi][ni]);

        asm volatile("s_waitcnt vmcnt(4)" ::: "memory");   // tile t+1 landed
        __builtin_amdgcn_s_barrier();
        char* ta = aR; aR = aN; aN = aP; aP = ta;
        char* tb = bR; bR = bN; bN = bP; bP = tb;
    }

    if (mat < 2) {
        __bf16* dst = (mat == 0) ? qa : ka;
        for (int mi = 0; mi < 4; ++mi)
            for (int r = 0; r < 4; ++r) {
                int p = am0 + wr + mi * 16 + quad * 4 + r;
                int g = b * NH_ + (p >> 7);
                int nbase = (p & 127) * 8;
                for (int ni = 0; ni < 4; ++ni) {
                    int o = bn0 + wc + ni * 16 + l16;
                    dst[((size_t)g * N_ + nbase + (o >> 6)) * HD_ + (o & 63)] =
                        (__bf16)acc[mi][ni][r];
                }
            }
    } else {
        for (int mi = 0; mi < 4; ++mi)
            for (int r = 0; r < 4; ++r) {
                int o = am0 + wr + mi * 16 + quad * 4 + r;
                int m = o & 63, i = o >> 6;
                for (int ni = 0; ni < 4; ++ni) {
                    int p = bn0 + wc + ni * 16 + l16;
                    int g = b * NH_ + (p >> 7);
                    vt[((size_t)g * HD_ + m) * N_ + (p & 127) * 8 + i] =
                        (__bf16)acc[mi][ni][r];
                }
            }
    }
}

// ----------------------------------------------------- K2: flash attention
// 256 blocks (XCD swizzle), 8 waves x 32 queries (256 q/block); K/V tiles
// triple-buffered via gload_lds (2 loads/wave/iter), counted vmcnt(2).
// Zero-move P: PV uses kv(quad,e)=32h+16(e>>2)+4quad+(e&3); B-operand is
// lane-local packed exp2, A-operand (V) read as 2x ds_read_b64.
__global__ __launch_bounds__(512) void k_attn(const __bf16* __restrict__ qa,
                                              const __bf16* __restrict__ ka,
                                              const __bf16* __restrict__ vt,
                                              __bf16* __restrict__ ap) {
    __shared__ __bf16 Kb[3][4096];              // 3 x 8KB  (64 rows x 128B)
    __shared__ __bf16 Vb[3][4096];              // 3 x 8KB  (64 d-rows x 128B)
    int blk = blockIdx.x;
    int g  = ((blk & 7) << 3) | ((blk >> 3) & 7);
    int qb = blk >> 6;                          // 4 q-blocks of 256
    int tid = threadIdx.x, lane = tid & 63, wid = tid >> 6;   // wid 0..7
    int quad = lane >> 4, l16 = lane & 15;
    int q0 = qb * 256 + wid * 32;

    const __bf16* qp = qa + (size_t)g * N_ * HD_;
    const char* kbb = (const char*)(ka + (size_t)g * N_ * HD_);   // row j: 128B
    const char* vbb = (const char*)(vt + (size_t)g * HD_ * N_);   // row d: 2048B

    bf16x8 qA0 = *(const bf16x8*)(qp + (size_t)(q0 + l16) * HD_ + quad * 8);
    bf16x8 qA1 = *(const bf16x8*)(qp + (size_t)(q0 + l16) * HD_ + 32 + quad * 8);
    bf16x8 qB0 = *(const bf16x8*)(qp + (size_t)(q0 + 16 + l16) * HD_ + quad * 8);
    bf16x8 qB1 = *(const bf16x8*)(qp + (size_t)(q0 + 16 + l16) * HD_ + 32 + quad * 8);

    int lrow = lane >> 3;                              // row within 8-row chunk
    int scol = ((lane & 7) * 16) ^ (lrow << 4);        // inverse-swizzled src col
    const char* kSrc = kbb + (size_t)(wid * 8 + lrow) * 128  + scol;
    const char* vSrc = vbb + (size_t)(wid * 8 + lrow) * 2048 + scol;
    int wb = wid * 1024;                               // wave stages rows [8w,8w+8)

    char *kR = (char*)&Kb[0][0], *kN = (char*)&Kb[1][0], *kP = (char*)&Kb[2][0];
    char *vR = (char*)&Vb[0][0], *vN = (char*)&Vb[1][0], *vP = (char*)&Vb[2][0];

    // prologue: tiles 0,1 -> R,N (2+2 loads/wave); wait tile0; barrier
    gload16(kSrc,        kR + wb);
    gload16(vSrc,        vR + wb);
    gload16(kSrc + 8192, kN + wb);     // tile1: +64 K-rows
    gload16(vSrc + 128,  vN + wb);     // tile1: +64 kv-cols
    asm volatile("s_waitcnt vmcnt(2)" ::: "memory");
    __builtin_amdgcn_s_barrier();

    float liA = 0.f, liB = 0.f;
    f32x4 oA[4] = {}, oB[4] = {};
    const float sc = 0.125f * 1.44269504088896340736f;   // SCALE * log2(e)
    const int fsw  = (l16 & 7) << 4;                     // frag byte swizzle

    union V8 { bf16x8 v8; bf16x4 v4[2]; };

    for (int t = 0; t < 16; ++t) {
        // 1) issue staging of tile t+2 into P (wraps on last iters; unused)
        int jn = ((t + 2) & 15) * 64;
        gload16(kSrc + (size_t)jn * 128, kP + wb);
        gload16(vSrc + jn * 2,           vP + wb);

        // 2) K frags from LDS + S-MFMA
        bf16x8 kc0[4], kc1[4];
        for (int tt = 0; tt < 4; ++tt) {
            int rb = (tt * 16 + l16) * 128;
            kc0[tt] = *(const bf16x8*)(kR + rb + ((quad * 16) ^ fsw));
            kc1[tt] = *(const bf16x8*)(kR + rb + ((64 + quad * 16) ^ fsw));
        }
        f32x4 sA[4] = {}, sB[4] = {};
        for (int tt = 0; tt < 4; ++tt) {
            sA[tt] = MFMA16(kc0[tt], qA0, sA[tt]);
            sA[tt] = MFMA16(kc1[tt], qA1, sA[tt]);
            sB[tt] = MFMA16(kc0[tt], qB0, sB[tt]);
            sB[tt] = MFMA16(kc1[tt], qB1, sB[tt]);
        }

        // 3) V frags: per (h,dd) two b64 reads at kv-cols 64h+8quad, +32
        //    (each within one 16B granule -> granule-XOR swizzle valid)
        V8 av[2][4];
        for (int h = 0; h < 2; ++h)
            for (int dd = 0; dd < 4; ++dd) {
                int rb = (dd * 16 + l16) * 128;
                av[h][dd].v4[0] = *(const bf16x4*)(vR + rb + ((h * 64 + quad * 8) ^ fsw));
                av[h][dd].v4[1] = *(const bf16x4*)(vR + rb + ((h * 64 + 32 + quad * 8) ^ fsw));
            }

        // 4) static softmax in-register: P packed lane-locally, no LDS
        bf16x8 paf[2], pbf[2];
        for (int tt = 0; tt < 4; ++tt)
            for (int r = 0; r < 4; ++r) {
                float pvA = exp2f(sA[tt][r] * sc);
                float pvB = exp2f(sB[tt][r] * sc);
                liA += pvA; liB += pvB;
                paf[tt >> 1][(tt & 1) * 4 + r] = (__bf16)pvA;
                pbf[tt >> 1][(tt & 1) * 4 + r] = (__bf16)pvB;
            }

        // 5) PV-MFMA (kv-order matches on both operands -> correct)
        for (int h = 0; h < 2; ++h)
            for (int dd = 0; dd < 4; ++dd) {
                oA[dd] = MFMA16(av[h][dd].v8, paf[h], oA[dd]);
                oB[dd] = MFMA16(av[h][dd].v8, pbf[h], oB[dd]);
            }

        // 6) tile t+1 landed (t+2's 2 loads stay in flight across barrier)
        asm volatile("s_waitcnt vmcnt(2)" ::: "memory");
        __builtin_amdgcn_s_barrier();
        char* tk = kR; kR = kN; kN = kP; kP = tk;
        char* tv = vR; vR = vN; vN = vP; vP = tv;
    }

    // one deferred li reduction across the 4 quads sharing each q
    liA += __shfl_xor(liA, 16, 64); liA += __shfl_xor(liA, 32, 64);
    liB += __shfl_xor(liB, 16, 64); liB += __shfl_xor(liB, 32, 64);

    int b = g >> 3, hi = g & 7;
    float invA = 1.0f / liA, invB = 1.0f / liB;
    int nA = q0 + l16, nB = q0 + 16 + l16;
    __bf16* dA = ap + ((size_t)(b * N_ + hi * 128 + (nA >> 3))) * C_ + (nA & 7) * 64;
    __bf16* dB = ap + ((size_t)(b * N_ + hi * 128 + (nB >> 3))) * C_ + (nB & 7) * 64;
    for (int dd = 0; dd < 4; ++dd) {
        bf16x4 oa, ob;
        for (int r = 0; r < 4; ++r) {
            oa[r] = (__bf16)(oA[dd][r] * invA);
            ob[r] = (__bf16)(oB[dd][r] * invB);
        }
        *(bf16x4*)(dA + dd * 16 + quad * 4) = oa;
        *(bf16x4*)(dB + dd * 16 + quad * 4) = ob;
    }
}

// --------------------------------------------- K3: out-projection (wo GEMM)
// Same triple-buffered staged-GEMM structure as k_qkv.
__global__ __launch_bounds__(256) void k_oproj(const __bf16* __restrict__ apm,
                                               const __bf16* __restrict__ wob,
                                               __bf16* __restrict__ o0) {
    __shared__ __bf16 As[3][4096];
    __shared__ __bf16 Bs[3][4096];
    int blk = blockIdx.x;
    int b = blk >> 5, tile = blk & 31;
    int mt = tile >> 2, nt = tile & 3;
    int tid = threadIdx.x, lane = tid & 63, wid = tid >> 6;
    int quad = lane >> 4, l16 = lane & 15;
    int am0 = mt * 128, bn0 = nt * 128;
    int wr = (wid >> 1) * 64, wc = (wid & 1) * 64;
    const __bf16* A = apm + (size_t)b * N_ * C_;

    int lrow = wid * 16 + (lane >> 2);
    int scol = ((lane & 3) * 16) ^ ((lrow & 3) << 4);
    const char* aS0 = (const char*)A   + (size_t)(am0 + lrow) * 1024 + scol;
    const char* aS1 = aS0 + 65536;
    const char* bS0 = (const char*)wob + (size_t)(bn0 + lrow) * 1024 + scol;
    const char* bS1 = bS0 + 65536;
    int wb = wid * 1024;

    char *aR = (char*)&As[0][0], *aN = (char*)&As[1][0], *aP = (char*)&As[2][0];
    char *bR = (char*)&Bs[0][0], *bN = (char*)&Bs[1][0], *bP = (char*)&Bs[2][0];

    gload16(aS0,      aR + wb);  gload16(aS1,      aR + wb + 4096);
    gload16(bS0,      bR + wb);  gload16(bS1,      bR + wb + 4096);
    gload16(aS0 + 64, aN + wb);  gload16(aS1 + 64, aN + wb + 4096);
    gload16(bS0 + 64, bN + wb);  gload16(bS1 + 64, bN + wb + 4096);
    asm volatile("s_waitcnt vmcnt(4)" ::: "memory");
    __builtin_amdgcn_s_barrier();

    f32x4 acc[4][4] = {};
    const int fo = (quad * 16) ^ ((l16 & 3) << 4);
    for (int t = 0; t < 16; ++t) {
        int kb = ((t + 2) & 15) * 64;
        gload16(aS0 + kb, aP + wb);  gload16(aS1 + kb, aP + wb + 4096);
        gload16(bS0 + kb, bP + wb);  gload16(bS1 + kb, bP + wb + 4096);

        bf16x8 af[4], bfr[4];
        for (int i = 0; i < 4; ++i)
            af[i]  = *(const bf16x8*)(aR + (wr + i * 16 + l16) * 64 + fo);
        for (int i = 0; i < 4; ++i)
            bfr[i] = *(const bf16x8*)(bR + (wc + i * 16 + l16) * 64 + fo);
        for (int mi = 0; mi < 4; ++mi)
            for (int ni = 0; ni < 4; ++ni)
                acc[mi][ni] = MFMA16(af[mi], bfr[ni], acc[mi][ni]);

        asm volatile("s_waitcnt vmcnt(4)" ::: "memory");
        __builtin_amdgcn_s_barrier();
        char* ta = aR; aR = aN; aN = aP; aP = ta;
        char* tb = bR; bR = bN; bN = bP; bP = tb;
    }
    for (int mi = 0; mi < 4; ++mi)
        for (int r = 0; r < 4; ++r) {
            int p = am0 + wr + mi * 16 + quad * 4 + r;
            __bf16* dst = o0 + ((size_t)(b * N_ + p)) * C_;
            for (int ni = 0; ni < 4; ++ni)
                dst[bn0 + wc + ni * 16 + l16] = (__bf16)acc[mi][ni][r];
        }
}

// ------------------- K4: LN(C) + gamma*(.) + residual -> out f32 [b][c][p]
__global__ __launch_bounds__(256) void k_ln(const __bf16* __restrict__ o0,
                                            const float* __restrict__ x,
                                            const float* __restrict__ lng,
                                            const float* __restrict__ lnb,
                                            const float* __restrict__ gm,
                                            float* __restrict__ out) {
    __shared__ __bf16 tile[32][C_ + 4];
    int blk = blockIdx.x;
    int b = blk >> 5, pt = blk & 31;
    int p0 = pt * 32;
    int tid = threadIdx.x, lane = tid & 63, wid = tid >> 6;
    float g = gm[0];
    float lg[8], lb[8];
    *(f32x4*)&lg[0] = *(const f32x4*)(lng + lane * 8);
    *(f32x4*)&lg[4] = *(const f32x4*)(lng + lane * 8 + 4);
    *(f32x4*)&lb[0] = *(const f32x4*)(lnb + lane * 8);
    *(f32x4*)&lb[4] = *(const f32x4*)(lnb + lane * 8 + 4);

    for (int i = 0; i < 8; ++i) {
        int p = wid * 8 + i;
        bf16x8 v = *(const bf16x8*)(o0 + ((size_t)(b * N_ + p0 + p)) * C_ + lane * 8);
        float f[8], s = 0.f, ss = 0.f;
        for (int j = 0; j < 8; ++j) { f[j] = (float)v[j]; s += f[j]; ss += f[j] * f[j]; }
        for (int d = 1; d < 64; d <<= 1) { s += __shfl_xor(s, d, 64); ss += __shfl_xor(ss, d, 64); }
        float mean = s * (1.f / 512.f);
        float var  = ss * (1.f / 512.f) - mean * mean;
        float rstd = rsqrtf(fmaxf(var, 0.f) + 1e-5f);
        bf16x4 o1, o2;
        for (int j = 0; j < 4; ++j)
            o1[j] = (__bf16)(g * ((f[j] - mean) * rstd * lg[j] + lb[j]));
        for (int j = 0; j < 4; ++j)
            o2[j] = (__bf16)(g * ((f[j + 4] - mean) * rstd * lg[j + 4] + lb[j + 4]));
        __bf16* dst = &tile[p][lane * 8];
        *(bf16x4*)dst = o1;
        *(bf16x4*)(dst + 4) = o2;
    }
    __syncthreads();
    for (int it = 0; it < 16; ++it) {
        int task = it * 256 + tid;
        int c = task >> 3, p4 = (task & 7) * 4;
        f32x4 xr = *(const f32x4*)(x + ((size_t)(b * C_ + c)) * N_ + p0 + p4);
        f32x4 o;
        for (int j = 0; j < 4; ++j)
            o[j] = (float)tile[p4 + j][c] + xr[j];
        *(f32x4*)(out + ((size_t)(b * C_ + c)) * N_ + p0 + p4) = o;
    }
}

// ======================= fallback (R8-proven scalar pipeline, f32)
__global__ void k_qkv8f(const float* __restrict__ x, const float* __restrict__ wq,
                        const float* __restrict__ wk, const float* __restrict__ wv,
                        float* __restrict__ qa, float* __restrict__ ka,
                        float* __restrict__ va, int g0) {
    int idx = blockIdx.x * 256 + threadIdx.x;
    int m = idx & 63, n = (idx >> 6) & 1023, Gl = (idx >> 16) & 1, mat = idx >> 17;
    int G = g0 + Gl, b = G >> 3, hb = G & 7;
    int p = hb * 128 + (n >> 3), o = (n & 7) * 64 + m;
    const float* w = (mat == 0) ? wq : (mat == 1) ? wk : wv;
    float acc = 0.f;
    for (int c = 0; c < C_; ++c)
        acc += w[(size_t)o * C_ + c] * x[((size_t)b * C_ + c) * N_ + p];
    float* dst = (mat == 0) ? qa : (mat == 1) ? ka : va;
    dst[((size_t)Gl * N_ + n) * HD_ + m] = acc;
}
__global__ void k_attn8f(const float* __restrict__ qa, const float* __restrict__ ka,
                         const float* __restrict__ va, float* __restrict__ ac, int g0) {
    int idx = blockIdx.x * 256 + threadIdx.x;
    int i = idx & 1023, Gl = (idx >> 10) & 1, G = g0 + Gl;
    const float* qrow = qa + ((size_t)Gl * N_ + i) * HD_;
    float q[HD_];
    for (int m = 0; m < HD_; ++m) q[m] = qrow[m];
    const float* kb = ka + (size_t)Gl * N_ * HD_;
    const float* vb = va + (size_t)Gl * N_ * HD_;
    float mx = -1e30f;
    for (int j = 0; j < N_; ++j) {
        float s = 0.f;
        for (int m = 0; m < HD_; ++m) s += q[m] * kb[j * HD_ + m];
        mx = fmaxf(mx, s);
    }
    mx *= 0.125f;
    float l = 0.f, ov[HD_];
    for (int m = 0; m < HD_; ++m) ov[m] = 0.f;
    for (int j = 0; j < N_; ++j) {
        float s = 0.f;
        for (int m = 0; m < HD_; ++m) s += q[m] * kb[j * HD_ + m];
        float pj = __expf(s * 0.125f - mx);
        l += pj;
        for (int m = 0; m < HD_; ++m) ov[m] += pj * vb[j * HD_ + m];
    }
    float inv = 1.0f / l;
    int b = G >> 3, hb = G & 7;
    int p = hb * 128 + (i >> 3), cb = (i & 7) * 64;
    for (int m = 0; m < HD_; ++m)
        ac[((size_t)b * C_ + cb + m) * N_ + p] = ov[m] * inv;
}
__global__ void k_oln8f(float* __restrict__ ac, const float* __restrict__ wo,
                        const float* __restrict__ x, const float* __restrict__ lng,
                        const float* __restrict__ lnb, const float* __restrict__ gm) {
    int tid = threadIdx.x, lane = tid & 63, wid = tid >> 6;
    int bp = blockIdx.x * 4 + wid;
    int b = bp >> 10, p = bp & 1023;
    float oc[8];
    for (int h = 0; h < 8; ++h) oc[h] = 0.f;
    for (int c = 0; c < C_; ++c) {
        float cv = ac[((size_t)b * C_ + c) * N_ + p];
        for (int h = 0; h < 8; ++h)
            oc[h] += wo[(size_t)(h * 64 + lane) * C_ + c] * cv;
    }
    float s = 0.f, ss = 0.f;
    for (int h = 0; h < 8; ++h) { s += oc[h]; ss += oc[h] * oc[h]; }
    for (int d = 1; d < 64; d <<= 1) { s += __shfl_xor(s, d, 64); ss += __shfl_xor(ss, d, 64); }
    float mean = s * (1.f / 512.f);
    float var  = ss * (1.f / 512.f) - mean * mean;
    float rstd = rsqrtf(fmaxf(var, 0.f) + 1e-5f);
    float g = gm[0];
    for (int h = 0; h < 8; ++h) {
        int o = h * 64 + lane;
        float xv = x[((size_t)b * C_ + o) * N_ + p];
        ac[((size_t)b * C_ + o) * N_ + p] =
            g * ((oc[h] - mean) * rstd * lng[o] + lnb[o]) + xv;
    }
}

// ---------------------------------------------------------------------------
extern "C" void kernel_launch(void* const* d_in, const int* in_sizes, int n_in,
                              void* d_out, int out_size, void* d_ws, size_t ws_size,
                              hipStream_t stream) {
    const float* x   = (const float*)d_in[0];
    const float* wq  = (const float*)d_in[1];
    const float* wk  = (const float*)d_in[2];
    const float* wv  = (const float*)d_in[3];
    const float* wo  = (const float*)d_in[4];
    const float* lng = (const float*)d_in[5];
    const float* lnb = (const float*)d_in[6];
    const float* gm  = (const float*)d_in[7];
    float* out = (float*)d_out;
    char* wsb = (char*)d_ws;

    if (ws_size >= ((size_t)18 << 20)) {
        __bf16* xt   = (__bf16*)wsb;
        __bf16* wcat = (__bf16*)(wsb + ((size_t)8 << 20));
        __bf16* Qa   = (__bf16*)(wsb + ((size_t)10 << 20));
        __bf16* Ka   = (__bf16*)d_out;
        __bf16* VaT  = (__bf16*)((char*)d_out + ((size_t)8 << 20));
        __bf16* ap   = xt;
        __bf16* o0   = Qa;
        __bf16* wob  = wcat + 3 * 262144;

        k_prep  <<<2048, 256, 0, stream>>>(x, wq, wk, wv, wo, xt, wcat);
        k_qkv   <<<768,  256, 0, stream>>>(xt, wcat, Qa, Ka, VaT);
        k_attn  <<<256,  512, 0, stream>>>(Qa, Ka, VaT, ap);
        k_oproj <<<256,  256, 0, stream>>>(ap, wob, o0);
        k_ln    <<<256,  256, 0, stream>>>(o0, x, lng, lnb, gm, out);
    } else {
        float* qa = (float*)(wsb + 256);
        float* ka = qa + 2 * N_ * HD_;
        float* va = ka + 2 * N_ * HD_;
        for (int g0 = 0; g0 < 64; g0 += 2) {
            k_qkv8f <<<1536, 256, 0, stream>>>(x, wq, wk, wv, qa, ka, va, g0);
            k_attn8f<<<8,    256, 0, stream>>>(qa, ka, va, out, g0);
        }
        k_oln8f<<<2048, 256, 0, stream>>>(out, wo, x, lng, lnb, gm);
    }
}

// Round 8
// 163.735 us; speedup vs baseline: 6.2804x; 6.2804x over previous
//
#include <hip/hip_runtime.h>
#include <hip/hip_bf16.h>

// R21: R20 zero-move-P with the scratch-codegen bug fixed.
// R20 post-mortem: 23x regression (VALUBusy 80%, MfmaUtil 0.7%) = rule #20 --
// union type-punning (V8) + vector writes via loop-var indices put P/V frags
// in scratch / per-element insert chains.  Fix: __builtin_shufflevector to
// merge the two bf16x4 V-reads into bf16x8 (pure SSA), and #pragma unroll on
// every small loop so all vector indices are compile-time constants.
// Algorithm unchanged from R20 (passed correctness): PV kv-bijection
// kv(quad,e)=32h+16(e>>2)+4quad+(e&3); P lane-local, V as 2x b64 reads.
// B=8, C=512, N=1024, NH=8, HD=64.

#define B_  8
#define C_  512
#define N_  1024
#define NH_ 8
#define HD_ 64

typedef __bf16 bf16x8 __attribute__((ext_vector_type(8)));
typedef __bf16 bf16x4 __attribute__((ext_vector_type(4)));
typedef float  f32x4  __attribute__((ext_vector_type(4)));

#define MFMA16(a, b, c) __builtin_amdgcn_mfma_f32_16x16x32_bf16((a), (b), (c), 0, 0, 0)

__device__ __forceinline__ void gload16(const void* g, void* l) {
    __builtin_amdgcn_global_load_lds(
        (const __attribute__((address_space(1))) unsigned int*)g,
        (__attribute__((address_space(3))) unsigned int*)l, 16, 0, 0);
}

// -------------------- K0: merged prep.  blk<1024: x -> xt; else weights -> wcat
__global__ __launch_bounds__(256) void k_prep(const float* __restrict__ x,
                                              const float* __restrict__ wq,
                                              const float* __restrict__ wk,
                                              const float* __restrict__ wv,
                                              const float* __restrict__ wo,
                                              __bf16* __restrict__ xt,
                                              __bf16* __restrict__ wcat) {
    __shared__ float tile[64][68];
    int blk = blockIdx.x;
    int tid = threadIdx.x;
    if (blk < 1024) {
        int b   = blk >> 7;
        int rem = blk & 127;
        int ct  = rem >> 4;
        int pt  = rem & 15;
        int c0 = ct * 64, p0 = pt * 64;
        for (int i = 0; i < 4; ++i) {
            int vi = i * 256 + tid;
            int c = vi >> 4, p4 = (vi & 15) * 4;
            f32x4 v = *(const f32x4*)(x + ((size_t)(b * C_ + c0 + c)) * N_ + p0 + p4);
            *(f32x4*)&tile[c][p4] = v;
        }
        __syncthreads();
        for (int i = 0; i < 4; ++i) {
            int vi = i * 256 + tid;
            int p = vi >> 4, c4 = (vi & 15) * 4;
            bf16x4 v;
            for (int j = 0; j < 4; ++j) v[j] = (__bf16)tile[c4 + j][p];
            *(bf16x4*)(xt + ((size_t)(b * N_ + p0 + p)) * C_ + c0 + c4) = v;
        }
    } else {
        int idx = (blk - 1024) * 256 + tid;
        int mat = idx >> 16;
        int off = (idx & 65535) * 4;
        const float* w = (mat == 0) ? wq : (mat == 1) ? wk : (mat == 2) ? wv : wo;
        f32x4 v = *(const f32x4*)(w + off);
        bf16x4 o;
        for (int j = 0; j < 4; ++j) o[j] = (__bf16)v[j];
        *(bf16x4*)(wcat + (size_t)mat * 262144 + off) = o;
    }
}

// ------------------------------------------------- K1: QKV projection (MFMA)
// 128x128 tile, BK=32, triple-buffered gload_lds staging, counted vmcnt.
__global__ __launch_bounds__(256) void k_qkv(const __bf16* __restrict__ xt,
                                             const __bf16* __restrict__ wcat,
                                             __bf16* __restrict__ qa,
                                             __bf16* __restrict__ ka,
                                             __bf16* __restrict__ vt) {
    __shared__ __bf16 As[3][4096];               // 3 x 8KB (128 rows x 64B)
    __shared__ __bf16 Bs[3][4096];
    int blk  = blockIdx.x;
    int mat  = blk >> 8;
    int rem  = blk & 255;
    int b    = rem >> 5;
    int tile = rem & 31;
    int tid = threadIdx.x, lane = tid & 63, wid = tid >> 6;
    int quad = lane >> 4, l16 = lane & 15;

    const __bf16* w = wcat + (size_t)mat * 262144;
    const __bf16 *A, *Bm;
    int am0, bn0;
    if (mat < 2) {
        int mt = tile >> 2, nt = tile & 3;
        A   = xt + (size_t)b * N_ * C_;  am0 = mt * 128;
        Bm  = w;                         bn0 = nt * 128;
    } else {
        int mt = tile & 3, nt = tile >> 2;
        A   = w;                         am0 = mt * 128;
        Bm  = xt + (size_t)b * N_ * C_;  bn0 = nt * 128;
    }
    int wr = (wid >> 1) * 64, wc = (wid & 1) * 64;   // wave tile offsets

    int lrow = wid * 16 + (lane >> 2);
    int scol = ((lane & 3) * 16) ^ ((lrow & 3) << 4);
    const char* aS0 = (const char*)A  + (size_t)(am0 + lrow) * 1024 + scol;
    const char* aS1 = aS0 + 65536;                   // +64 rows
    const char* bS0 = (const char*)Bm + (size_t)(bn0 + lrow) * 1024 + scol;
    const char* bS1 = bS0 + 65536;
    int wb = wid * 1024;

    // rotating buffer base pointers: R=read, N=next (landed), P=prefetch-dest
    char *aR = (char*)&As[0][0], *aN = (char*)&As[1][0], *aP = (char*)&As[2][0];
    char *bR = (char*)&Bs[0][0], *bN = (char*)&Bs[1][0], *bP = (char*)&Bs[2][0];

    // prologue: tiles 0,1 -> R,N (8 loads); wait tile0 (vmcnt<=4); barrier
    gload16(aS0,      aR + wb);  gload16(aS1,      aR + wb + 4096);
    gload16(bS0,      bR + wb);  gload16(bS1,      bR + wb + 4096);
    gload16(aS0 + 64, aN + wb);  gload16(aS1 + 64, aN + wb + 4096);
    gload16(bS0 + 64, bN + wb);  gload16(bS1 + 64, bN + wb + 4096);
    asm volatile("s_waitcnt vmcnt(4)" ::: "memory");
    __builtin_amdgcn_s_barrier();

    f32x4 acc[4][4] = {};
    const int fo = (quad * 16) ^ ((l16 & 3) << 4);   // frag byte col (swz'd)
    for (int t = 0; t < 16; ++t) {
        int kb = ((t + 2) & 15) * 64;                // tile t+2 byte offset
        gload16(aS0 + kb, aP + wb);  gload16(aS1 + kb, aP + wb + 4096);
        gload16(bS0 + kb, bP + wb);  gload16(bS1 + kb, bP + wb + 4096);

        bf16x8 af[4], bfr[4];
        for (int i = 0; i < 4; ++i)
            af[i]  = *(const bf16x8*)(aR + (wr + i * 16 + l16) * 64 + fo);
        for (int i = 0; i < 4; ++i)
            bfr[i] = *(const bf16x8*)(bR + (wc + i * 16 + l16) * 64 + fo);
        for (int mi = 0; mi < 4; ++mi)
            for (int ni = 0; ni < 4; ++ni)
                acc[mi][ni] = MFMA16(af[mi], bfr[ni], acc[mi][ni]);

        asm volatile("s_waitcnt vmcnt(4)" ::: "memory");   // tile t+1 landed
        __builtin_amdgcn_s_barrier();
        char* ta = aR; aR = aN; aN = aP; aP = ta;
        char* tb = bR; bR = bN; bN = bP; bP = tb;
    }

    if (mat < 2) {
        __bf16* dst = (mat == 0) ? qa : ka;
        for (int mi = 0; mi < 4; ++mi)
            for (int r = 0; r < 4; ++r) {
                int p = am0 + wr + mi * 16 + quad * 4 + r;
                int g = b * NH_ + (p >> 7);
                int nbase = (p & 127) * 8;
                for (int ni = 0; ni < 4; ++ni) {
                    int o = bn0 + wc + ni * 16 + l16;
                    dst[((size_t)g * N_ + nbase + (o >> 6)) * HD_ + (o & 63)] =
                        (__bf16)acc[mi][ni][r];
                }
            }
    } else {
        for (int mi = 0; mi < 4; ++mi)
            for (int r = 0; r < 4; ++r) {
                int o = am0 + wr + mi * 16 + quad * 4 + r;
                int m = o & 63, i = o >> 6;
                for (int ni = 0; ni < 4; ++ni) {
                    int p = bn0 + wc + ni * 16 + l16;
                    int g = b * NH_ + (p >> 7);
                    vt[((size_t)g * HD_ + m) * N_ + (p & 127) * 8 + i] =
                        (__bf16)acc[mi][ni][r];
                }
            }
    }
}

// ----------------------------------------------------- K2: flash attention
// 256 blocks (XCD swizzle), 8 waves x 32 queries (256 q/block); K/V tiles
// triple-buffered via gload_lds (2 loads/wave/iter), counted vmcnt(2).
// Zero-move P: PV uses kv(quad,e)=32h+16(e>>2)+4quad+(e&3); B-operand is
// lane-local packed exp2, A-operand (V) = 2x b64 merged via shufflevector.
__global__ __launch_bounds__(512) void k_attn(const __bf16* __restrict__ qa,
                                              const __bf16* __restrict__ ka,
                                              const __bf16* __restrict__ vt,
                                              __bf16* __restrict__ ap) {
    __shared__ __bf16 Kb[3][4096];              // 3 x 8KB  (64 rows x 128B)
    __shared__ __bf16 Vb[3][4096];              // 3 x 8KB  (64 d-rows x 128B)
    int blk = blockIdx.x;
    int g  = ((blk & 7) << 3) | ((blk >> 3) & 7);
    int qb = blk >> 6;                          // 4 q-blocks of 256
    int tid = threadIdx.x, lane = tid & 63, wid = tid >> 6;   // wid 0..7
    int quad = lane >> 4, l16 = lane & 15;
    int q0 = qb * 256 + wid * 32;

    const __bf16* qp = qa + (size_t)g * N_ * HD_;
    const char* kbb = (const char*)(ka + (size_t)g * N_ * HD_);   // row j: 128B
    const char* vbb = (const char*)(vt + (size_t)g * HD_ * N_);   // row d: 2048B

    bf16x8 qA0 = *(const bf16x8*)(qp + (size_t)(q0 + l16) * HD_ + quad * 8);
    bf16x8 qA1 = *(const bf16x8*)(qp + (size_t)(q0 + l16) * HD_ + 32 + quad * 8);
    bf16x8 qB0 = *(const bf16x8*)(qp + (size_t)(q0 + 16 + l16) * HD_ + quad * 8);
    bf16x8 qB1 = *(const bf16x8*)(qp + (size_t)(q0 + 16 + l16) * HD_ + 32 + quad * 8);

    int lrow = lane >> 3;                              // row within 8-row chunk
    int scol = ((lane & 7) * 16) ^ (lrow << 4);        // inverse-swizzled src col
    const char* kSrc = kbb + (size_t)(wid * 8 + lrow) * 128  + scol;
    const char* vSrc = vbb + (size_t)(wid * 8 + lrow) * 2048 + scol;
    int wb = wid * 1024;                               // wave stages rows [8w,8w+8)

    char *kR = (char*)&Kb[0][0], *kN = (char*)&Kb[1][0], *kP = (char*)&Kb[2][0];
    char *vR = (char*)&Vb[0][0], *vN = (char*)&Vb[1][0], *vP = (char*)&Vb[2][0];

    // prologue: tiles 0,1 -> R,N (2+2 loads/wave); wait tile0; barrier
    gload16(kSrc,        kR + wb);
    gload16(vSrc,        vR + wb);
    gload16(kSrc + 8192, kN + wb);     // tile1: +64 K-rows
    gload16(vSrc + 128,  vN + wb);     // tile1: +64 kv-cols
    asm volatile("s_waitcnt vmcnt(2)" ::: "memory");
    __builtin_amdgcn_s_barrier();

    float liA = 0.f, liB = 0.f;
    f32x4 oA[4] = {}, oB[4] = {};
    const float sc = 0.125f * 1.44269504088896340736f;   // SCALE * log2(e)
    const int fsw  = (l16 & 7) << 4;                     // frag byte swizzle

    for (int t = 0; t < 16; ++t) {
        // 1) issue staging of tile t+2 into P (wraps on last iters; unused)
        int jn = ((t + 2) & 15) * 64;
        gload16(kSrc + (size_t)jn * 128, kP + wb);
        gload16(vSrc + jn * 2,           vP + wb);

        // 2) K frags from LDS + S-MFMA
        bf16x8 kc0[4], kc1[4];
#pragma unroll
        for (int tt = 0; tt < 4; ++tt) {
            int rb = (tt * 16 + l16) * 128;
            kc0[tt] = *(const bf16x8*)(kR + rb + ((quad * 16) ^ fsw));
            kc1[tt] = *(const bf16x8*)(kR + rb + ((64 + quad * 16) ^ fsw));
        }
        f32x4 sA[4] = {}, sB[4] = {};
#pragma unroll
        for (int tt = 0; tt < 4; ++tt) {
            sA[tt] = MFMA16(kc0[tt], qA0, sA[tt]);
            sA[tt] = MFMA16(kc1[tt], qA1, sA[tt]);
            sB[tt] = MFMA16(kc0[tt], qB0, sB[tt]);
            sB[tt] = MFMA16(kc1[tt], qB1, sB[tt]);
        }

        // 3) V frags: per (h,dd) two b64 reads at kv-cols 64h+8quad, +32;
        //    merged in-register via shufflevector (NO union / scratch).
        bf16x8 av[2][4];
#pragma unroll
        for (int h = 0; h < 2; ++h)
#pragma unroll
            for (int dd = 0; dd < 4; ++dd) {
                int rb = (dd * 16 + l16) * 128;
                bf16x4 lo = *(const bf16x4*)(vR + rb + ((h * 64 + quad * 8) ^ fsw));
                bf16x4 hi = *(const bf16x4*)(vR + rb + ((h * 64 + 32 + quad * 8) ^ fsw));
                av[h][dd] = __builtin_shufflevector(lo, hi, 0, 1, 2, 3, 4, 5, 6, 7);
            }

        // 4) static softmax in-register: P packed lane-locally, no LDS
        bf16x8 paf[2], pbf[2];
#pragma unroll
        for (int tt = 0; tt < 4; ++tt)
#pragma unroll
            for (int r = 0; r < 4; ++r) {
                float pvA = exp2f(sA[tt][r] * sc);
                float pvB = exp2f(sB[tt][r] * sc);
                liA += pvA; liB += pvB;
                paf[tt >> 1][(tt & 1) * 4 + r] = (__bf16)pvA;
                pbf[tt >> 1][(tt & 1) * 4 + r] = (__bf16)pvB;
            }

        // 5) PV-MFMA (kv-order matches on both operands -> correct)
#pragma unroll
        for (int h = 0; h < 2; ++h)
#pragma unroll
            for (int dd = 0; dd < 4; ++dd) {
                oA[dd] = MFMA16(av[h][dd], paf[h], oA[dd]);
                oB[dd] = MFMA16(av[h][dd], pbf[h], oB[dd]);
            }

        // 6) tile t+1 landed (t+2's 2 loads stay in flight across barrier)
        asm volatile("s_waitcnt vmcnt(2)" ::: "memory");
        __builtin_amdgcn_s_barrier();
        char* tk = kR; kR = kN; kN = kP; kP = tk;
        char* tv = vR; vR = vN; vN = vP; vP = tv;
    }

    // one deferred li reduction across the 4 quads sharing each q
    liA += __shfl_xor(liA, 16, 64); liA += __shfl_xor(liA, 32, 64);
    liB += __shfl_xor(liB, 16, 64); liB += __shfl_xor(liB, 32, 64);

    int b = g >> 3, hi = g & 7;
    float invA = 1.0f / liA, invB = 1.0f / liB;
    int nA = q0 + l16, nB = q0 + 16 + l16;
    __bf16* dA = ap + ((size_t)(b * N_ + hi * 128 + (nA >> 3))) * C_ + (nA & 7) * 64;
    __bf16* dB = ap + ((size_t)(b * N_ + hi * 128 + (nB >> 3))) * C_ + (nB & 7) * 64;
#pragma unroll
    for (int dd = 0; dd < 4; ++dd) {
        bf16x4 oa, ob;
#pragma unroll
        for (int r = 0; r < 4; ++r) {
            oa[r] = (__bf16)(oA[dd][r] * invA);
            ob[r] = (__bf16)(oB[dd][r] * invB);
        }
        *(bf16x4*)(dA + dd * 16 + quad * 4) = oa;
        *(bf16x4*)(dB + dd * 16 + quad * 4) = ob;
    }
}

// --------------------------------------------- K3: out-projection (wo GEMM)
// Same triple-buffered staged-GEMM structure as k_qkv.
__global__ __launch_bounds__(256) void k_oproj(const __bf16* __restrict__ apm,
                                               const __bf16* __restrict__ wob,
                                               __bf16* __restrict__ o0) {
    __shared__ __bf16 As[3][4096];
    __shared__ __bf16 Bs[3][4096];
    int blk = blockIdx.x;
    int b = blk >> 5, tile = blk & 31;
    int mt = tile >> 2, nt = tile & 3;
    int tid = threadIdx.x, lane = tid & 63, wid = tid >> 6;
    int quad = lane >> 4, l16 = lane & 15;
    int am0 = mt * 128, bn0 = nt * 128;
    int wr = (wid >> 1) * 64, wc = (wid & 1) * 64;
    const __bf16* A = apm + (size_t)b * N_ * C_;

    int lrow = wid * 16 + (lane >> 2);
    int scol = ((lane & 3) * 16) ^ ((lrow & 3) << 4);
    const char* aS0 = (const char*)A   + (size_t)(am0 + lrow) * 1024 + scol;
    const char* aS1 = aS0 + 65536;
    const char* bS0 = (const char*)wob + (size_t)(bn0 + lrow) * 1024 + scol;
    const char* bS1 = bS0 + 65536;
    int wb = wid * 1024;

    char *aR = (char*)&As[0][0], *aN = (char*)&As[1][0], *aP = (char*)&As[2][0];
    char *bR = (char*)&Bs[0][0], *bN = (char*)&Bs[1][0], *bP = (char*)&Bs[2][0];

    gload16(aS0,      aR + wb);  gload16(aS1,      aR + wb + 4096);
    gload16(bS0,      bR + wb);  gload16(bS1,      bR + wb + 4096);
    gload16(aS0 + 64, aN + wb);  gload16(aS1 + 64, aN + wb + 4096);
    gload16(bS0 + 64, bN + wb);  gload16(bS1 + 64, bN + wb + 4096);
    asm volatile("s_waitcnt vmcnt(4)" ::: "memory");
    __builtin_amdgcn_s_barrier();

    f32x4 acc[4][4] = {};
    const int fo = (quad * 16) ^ ((l16 & 3) << 4);
    for (int t = 0; t < 16; ++t) {
        int kb = ((t + 2) & 15) * 64;
        gload16(aS0 + kb, aP + wb);  gload16(aS1 + kb, aP + wb + 4096);
        gload16(bS0 + kb, bP + wb);  gload16(bS1 + kb, bP + wb + 4096);

        bf16x8 af[4], bfr[4];
        for (int i = 0; i < 4; ++i)
            af[i]  = *(const bf16x8*)(aR + (wr + i * 16 + l16) * 64 + fo);
        for (int i = 0; i < 4; ++i)
            bfr[i] = *(const bf16x8*)(bR + (wc + i * 16 + l16) * 64 + fo);
        for (int mi = 0; mi < 4; ++mi)
            for (int ni = 0; ni < 4; ++ni)
                acc[mi][ni] = MFMA16(af[mi], bfr[ni], acc[mi][ni]);

        asm volatile("s_waitcnt vmcnt(4)" ::: "memory");
        __builtin_amdgcn_s_barrier();
        char* ta = aR; aR = aN; aN = aP; aP = ta;
        char* tb = bR; bR = bN; bN = bP; bP = tb;
    }
    for (int mi = 0; mi < 4; ++mi)
        for (int r = 0; r < 4; ++r) {
            int p = am0 + wr + mi * 16 + quad * 4 + r;
            __bf16* dst = o0 + ((size_t)(b * N_ + p)) * C_;
            for (int ni = 0; ni < 4; ++ni)
                dst[bn0 + wc + ni * 16 + l16] = (__bf16)acc[mi][ni][r];
        }
}

// ------------------- K4: LN(C) + gamma*(.) + residual -> out f32 [b][c][p]
__global__ __launch_bounds__(256) void k_ln(const __bf16* __restrict__ o0,
                                            const float* __restrict__ x,
                                            const float* __restrict__ lng,
                                            const float* __restrict__ lnb,
                                            const float* __restrict__ gm,
                                            float* __restrict__ out) {
    __shared__ __bf16 tile[32][C_ + 4];
    int blk = blockIdx.x;
    int b = blk >> 5, pt = blk & 31;
    int p0 = pt * 32;
    int tid = threadIdx.x, lane = tid & 63, wid = tid >> 6;
    float g = gm[0];
    float lg[8], lb[8];
    *(f32x4*)&lg[0] = *(const f32x4*)(lng + lane * 8);
    *(f32x4*)&lg[4] = *(const f32x4*)(lng + lane * 8 + 4);
    *(f32x4*)&lb[0] = *(const f32x4*)(lnb + lane * 8);
    *(f32x4*)&lb[4] = *(const f32x4*)(lnb + lane * 8 + 4);

    for (int i = 0; i < 8; ++i) {
        int p = wid * 8 + i;
        bf16x8 v = *(const bf16x8*)(o0 + ((size_t)(b * N_ + p0 + p)) * C_ + lane * 8);
        float f[8], s = 0.f, ss = 0.f;
        for (int j = 0; j < 8; ++j) { f[j] = (float)v[j]; s += f[j]; ss += f[j] * f[j]; }
        for (int d = 1; d < 64; d <<= 1) { s += __shfl_xor(s, d, 64); ss += __shfl_xor(ss, d, 64); }
        float mean = s * (1.f / 512.f);
        float var  = ss * (1.f / 512.f) - mean * mean;
        float rstd = rsqrtf(fmaxf(var, 0.f) + 1e-5f);
        bf16x4 o1, o2;
        for (int j = 0; j < 4; ++j)
            o1[j] = (__bf16)(g * ((f[j] - mean) * rstd * lg[j] + lb[j]));
        for (int j = 0; j < 4; ++j)
            o2[j] = (__bf16)(g * ((f[j + 4] - mean) * rstd * lg[j + 4] + lb[j + 4]));
        __bf16* dst = &tile[p][lane * 8];
        *(bf16x4*)dst = o1;
        *(bf16x4*)(dst + 4) = o2;
    }
    __syncthreads();
    for (int it = 0; it < 16; ++it) {
        int task = it * 256 + tid;
        int c = task >> 3, p4 = (task & 7) * 4;
        f32x4 xr = *(const f32x4*)(x + ((size_t)(b * C_ + c)) * N_ + p0 + p4);
        f32x4 o;
        for (int j = 0; j < 4; ++j)
            o[j] = (float)tile[p4 + j][c] + xr[j];
        *(f32x4*)(out + ((size_t)(b * C_ + c)) * N_ + p0 + p4) = o;
    }
}

// ======================= fallback (R8-proven scalar pipeline, f32)
__global__ void k_qkv8f(const float* __restrict__ x, const float* __restrict__ wq,
                        const float* __restrict__ wk, const float* __restrict__ wv,
                        float* __restrict__ qa, float* __restrict__ ka,
                        float* __restrict__ va, int g0) {
    int idx = blockIdx.x * 256 + threadIdx.x;
    int m = idx & 63, n = (idx >> 6) & 1023, Gl = (idx >> 16) & 1, mat = idx >> 17;
    int G = g0 + Gl, b = G >> 3, hb = G & 7;
    int p = hb * 128 + (n >> 3), o = (n & 7) * 64 + m;
    const float* w = (mat == 0) ? wq : (mat == 1) ? wk : wv;
    float acc = 0.f;
    for (int c = 0; c < C_; ++c)
        acc += w[(size_t)o * C_ + c] * x[((size_t)b * C_ + c) * N_ + p];
    float* dst = (mat == 0) ? qa : (mat == 1) ? ka : va;
    dst[((size_t)Gl * N_ + n) * HD_ + m] = acc;
}
__global__ void k_attn8f(const float* __restrict__ qa, const float* __restrict__ ka,
                         const float* __restrict__ va, float* __restrict__ ac, int g0) {
    int idx = blockIdx.x * 256 + threadIdx.x;
    int i = idx & 1023, Gl = (idx >> 10) & 1, G = g0 + Gl;
    const float* qrow = qa + ((size_t)Gl * N_ + i) * HD_;
    float q[HD_];
    for (int m = 0; m < HD_; ++m) q[m] = qrow[m];
    const float* kb = ka + (size_t)Gl * N_ * HD_;
    const float* vb = va + (size_t)Gl * N_ * HD_;
    float mx = -1e30f;
    for (int j = 0; j < N_; ++j) {
        float s = 0.f;
        for (int m = 0; m < HD_; ++m) s += q[m] * kb[j * HD_ + m];
        mx = fmaxf(mx, s);
    }
    mx *= 0.125f;
    float l = 0.f, ov[HD_];
    for (int m = 0; m < HD_; ++m) ov[m] = 0.f;
    for (int j = 0; j < N_; ++j) {
        float s = 0.f;
        for (int m = 0; m < HD_; ++m) s += q[m] * kb[j * HD_ + m];
        float pj = __expf(s * 0.125f - mx);
        l += pj;
        for (int m = 0; m < HD_; ++m) ov[m] += pj * vb[j * HD_ + m];
    }
    float inv = 1.0f / l;
    int b = G >> 3, hb = G & 7;
    int p = hb * 128 + (i >> 3), cb = (i & 7) * 64;
    for (int m = 0; m < HD_; ++m)
        ac[((size_t)b * C_ + cb + m) * N_ + p] = ov[m] * inv;
}
__global__ void k_oln8f(float* __restrict__ ac, const float* __restrict__ wo,
                        const float* __restrict__ x, const float* __restrict__ lng,
                        const float* __restrict__ lnb, const float* __restrict__ gm) {
    int tid = threadIdx.x, lane = tid & 63, wid = tid >> 6;
    int bp = blockIdx.x * 4 + wid;
    int b = bp >> 10, p = bp & 1023;
    float oc[8];
    for (int h = 0; h < 8; ++h) oc[h] = 0.f;
    for (int c = 0; c < C_; ++c) {
        float cv = ac[((size_t)b * C_ + c) * N_ + p];
        for (int h = 0; h < 8; ++h)
            oc[h] += wo[(size_t)(h * 64 + lane) * C_ + c] * cv;
    }
    float s = 0.f, ss = 0.f;
    for (int h = 0; h < 8; ++h) { s += oc[h]; ss += oc[h] * oc[h]; }
    for (int d = 1; d < 64; d <<= 1) { s += __shfl_xor(s, d, 64); ss += __shfl_xor(ss, d, 64); }
    float mean = s * (1.f / 512.f);
    float var  = ss * (1.f / 512.f) - mean * mean;
    float rstd = rsqrtf(fmaxf(var, 0.f) + 1e-5f);
    float g = gm[0];
    for (int h = 0; h < 8; ++h) {
        int o = h * 64 + lane;
        float xv = x[((size_t)b * C_ + o) * N_ + p];
        ac[((size_t)b * C_ + o) * N_ + p] =
            g * ((oc[h] - mean) * rstd * lng[o] + lnb[o]) + xv;
    }
}

// ---------------------------------------------------------------------------
extern "C" void kernel_launch(void* const* d_in, const int* in_sizes, int n_in,
                              void* d_out, int out_size, void* d_ws, size_t ws_size,
                              hipStream_t stream) {
    const float* x   = (const float*)d_in[0];
    const float* wq  = (const float*)d_in[1];
    const float* wk  = (const float*)d_in[2];
    const float* wv  = (const float*)d_in[3];
    const float* wo  = (const float*)d_in[4];
    const float* lng = (const float*)d_in[5];
    const float* lnb = (const float*)d_in[6];
    const float* gm  = (const float*)d_in[7];
    float* out = (float*)d_out;
    char* wsb = (char*)d_ws;

    if (ws_size >= ((size_t)18 << 20)) {
        __bf16* xt   = (__bf16*)wsb;
        __bf16* wcat = (__bf16*)(wsb + ((size_t)8 << 20));
        __bf16* Qa   = (__bf16*)(wsb + ((size_t)10 << 20));
        __bf16* Ka   = (__bf16*)d_out;
        __bf16* VaT  = (__bf16*)((char*)d_out + ((size_t)8 << 20));
        __bf16* ap   = xt;
        __bf16* o0   = Qa;
        __bf16* wob  = wcat + 3 * 262144;

        k_prep  <<<2048, 256, 0, stream>>>(x, wq, wk, wv, wo, xt, wcat);
        k_qkv   <<<768,  256, 0, stream>>>(xt, wcat, Qa, Ka, VaT);
        k_attn  <<<256,  512, 0, stream>>>(Qa, Ka, VaT, ap);
        k_oproj <<<256,  256, 0, stream>>>(ap, wob, o0);
        k_ln    <<<256,  256, 0, stream>>>(o0, x, lng, lnb, gm, out);
    } else {
        float* qa = (float*)(wsb + 256);
        float* ka = qa + 2 * N_ * HD_;
        float* va = ka + 2 * N_ * HD_;
        for (int g0 = 0; g0 < 64; g0 += 2) {
            k_qkv8f <<<1536, 256, 0, stream>>>(x, wq, wk, wv, qa, ka, va, g0);
            k_attn8f<<<8,    256, 0, stream>>>(qa, ka, va, out, g0);
        }
        k_oln8f<<<2048, 256, 0, stream>>>(out, wo, x, lng, lnb, gm);
    }
}